// Round 2
// baseline (1255.045 us; speedup 1.0000x reference)
//
#include <hip/hip_runtime.h>

// Sylo forward: out[n,o,h,w] = rs[n,o,h] + cs[n,o,w] - P[n,o,h,w] + bias[o], diag=0
//   T[o,c] = L[o,c] @ L[o,c]^T (rank-4)
//   P = sum_c X[n,c] .* T[o,c]
//   rs[n,o,h] = sum_c sum_k X[n,c,h,k] * T[o,c,h,k]
//   cs[n,o,w] = sum_c sum_k X[n,c,k,w] * T[o,c,k,w]
//
// N=8, C_IN=4, C_OUT=64, DIM=512, RANK=4

#define DIMS 512
#define CIN 4
#define COUT 64
#define NB 8
#define RANKS 4

typedef float f32x4 __attribute__((ext_vector_type(4)));  // nontemporal-store-able

// ws layout (floats):
//   Lpk  [CIN][DIM][COUT*RANK]   = 4*512*256 = 524288   (2 MiB)
//   rs   [NB][COUT][DIM]         = 262144               (1 MiB)
//   cs   [NB][COUT][DIM]         = 262144               (1 MiB)
#define LPK_ELEMS (CIN * DIMS * COUT * RANKS)
#define SUMS_ELEMS (NB * COUT * DIMS)

// ---------------------------------------------------------------------------
// Kernel 0: pack L[o][c][k][r] -> Lpk[c][k][o*4+r]  (coalesced writes)
// ---------------------------------------------------------------------------
__global__ __launch_bounds__(256) void pack_L(const float* __restrict__ L,
                                              float* __restrict__ Lpk) {
    int idx = blockIdx.x * 256 + threadIdx.x;   // 524288 total
    int oc = idx & 255;
    int k  = (idx >> 8) & 511;
    int c  = idx >> 17;
    int o = oc >> 2, r = oc & 3;
    Lpk[idx] = L[((o * CIN + c) * DIMS + k) * RANKS + r];
}

// ---------------------------------------------------------------------------
// Kernel 1 (v3): rs (mode 0) and cs (mode 1).
// KEY CHANGE vs v1/v2: wave = input channel.  Each of the 4 waves owns one c
// and a FULL 16-row d-tile (float4 acc[16]); lane owns o=lane's 4 ranks.
//   -> per-wave Lpk stream = 512 KiB (its c slice), total 1 GiB L2 (was 4-8).
// X tile values are wave-uniform -> broadcast ds_read_b128 (conflict-free).
// Cross-wave (cross-c) reduction of the folded partials via 16 KB LDS.
// ---------------------------------------------------------------------------
#define XSTR 68            // Xsm row stride (floats); 16B-aligned, 2-way max
#define CSTR (16 * XSTR)   // per-c plane (1088 floats)

__global__ __launch_bounds__(256, 4) void sums_kernel(const float* __restrict__ X,
                                                      const float* __restrict__ Lpk,
                                                      float* __restrict__ sums) {
    const int mode = blockIdx.y;                 // 0: rs, 1: cs
    const int n    = blockIdx.x >> 5;            // 8
    const int d0   = (blockIdx.x & 31) << 4;     // 32 tiles of 16 rows
    const int t    = threadIdx.x;
    const int lane = t & 63;                     // o = lane (4 ranks per lane)
    const int w    = t >> 6;                     // wave id == input channel c

    __shared__ float smem[4608];  // Xsm [4][16][68]=4352 floats; reused as red
    const float4* __restrict__ Lpk4 = (const float4*)Lpk;

    float4 acc[16];
#pragma unroll
    for (int d = 0; d < 16; ++d) acc[d] = (float4){0.f, 0.f, 0.f, 0.f};

    const float* __restrict__ Xc = X + (size_t)(n * CIN + w) * DIMS * DIMS;

    for (int k0 = 0; k0 < DIMS; k0 += 64) {
        __syncthreads();  // protect previous tile's reads
        if (mode == 0) {
            // Xsm[w][d][kk] = X[n][w][d0+d][k0+kk]  (coalesced 64-wide)
#pragma unroll
            for (int j = 0; j < 16; ++j)
                smem[w * CSTR + j * XSTR + lane] = Xc[(d0 + j) * DIMS + k0 + lane];
        } else {
            // Xsm[w][d][kk] = X[n][w][k0+kk][d0+d]  (16-wide segments)
            int dd = lane & 15, kk0 = lane >> 4;
#pragma unroll
            for (int j = 0; j < 16; ++j)
                smem[w * CSTR + dd * XSTR + 4 * j + kk0] =
                    Xc[(k0 + 4 * j + kk0) * DIMS + d0 + dd];
        }
        __syncthreads();

#pragma unroll 2
        for (int k = 0; k < 64; k += 4) {
            float4 lv0 = Lpk4[(w * DIMS + k0 + k + 0) * 64 + lane];
            float4 lv1 = Lpk4[(w * DIMS + k0 + k + 1) * 64 + lane];
            float4 lv2 = Lpk4[(w * DIMS + k0 + k + 2) * 64 + lane];
            float4 lv3 = Lpk4[(w * DIMS + k0 + k + 3) * 64 + lane];
#pragma unroll
            for (int d = 0; d < 16; ++d) {
                float4 xv = *(const float4*)&smem[w * CSTR + d * XSTR + k];  // broadcast
                acc[d].x += xv.x * lv0.x + xv.y * lv1.x + xv.z * lv2.x + xv.w * lv3.x;
                acc[d].y += xv.x * lv0.y + xv.y * lv1.y + xv.z * lv2.y + xv.w * lv3.y;
                acc[d].z += xv.x * lv0.z + xv.y * lv1.z + xv.z * lv2.z + xv.w * lv3.z;
                acc[d].w += xv.x * lv0.w + xv.y * lv1.w + xv.z * lv2.w + xv.w * lv3.w;
            }
        }
    }

    // fold L[o,c,d,r] over this thread's 4 ranks -> per-c partial rs
    float rsp[16];
#pragma unroll
    for (int d = 0; d < 16; ++d) {
        float4 lf = Lpk4[(w * DIMS + d0 + d) * 64 + lane];
        rsp[d] = lf.x * acc[d].x + lf.y * acc[d].y + lf.z * acc[d].z + lf.w * acc[d].w;
    }

    // cross-wave (cross-c) reduction: red[(d*4+w)*65 + o]
    __syncthreads();  // smem reuse
    float* red = smem;
#pragma unroll
    for (int d = 0; d < 16; ++d)
        red[(d * 4 + w) * 65 + lane] = rsp[d];
    __syncthreads();

    float* __restrict__ dst = sums + (size_t)mode * SUMS_ELEMS + (size_t)n * COUT * DIMS + d0;
#pragma unroll
    for (int j = 0; j < 4; ++j) {
        int idx = 256 * j + t;   // = o*16 + d
        int d = idx & 15, o = idx >> 4;
        float v = red[(d * 4 + 0) * 65 + o] + red[(d * 4 + 1) * 65 + o] +
                  red[(d * 4 + 2) * 65 + o] + red[(d * 4 + 3) * 65 + o];
        dst[o * DIMS + d] = v;   // 16-lane 64B segments
    }
}

// ---------------------------------------------------------------------------
// Kernel 2 (v3): out[n,o,h,w] = rs + cs - P + bias, zero diagonal.
// Block: 4 consecutive o  x  32x32 (h,w) tile; 256 threads; thread owns one
// float4 row-segment per (n,o).  T slice in REGISTERS (4o x 4c float4 = 64
// VGPR); each X float4 load feeds 4 o's (16 fma / 16B).  LDS = 16 KB.
// Grid x = o-group (fastest) so consecutive blocks share X tiles in L2.
// ---------------------------------------------------------------------------
#define OPB 4

__global__ __launch_bounds__(256, 4) void final_kernel(const float* __restrict__ X,
                                                       const float* __restrict__ L,
                                                       const float* __restrict__ bias,
                                                       const float* __restrict__ sums,
                                                       float* __restrict__ out) {
    const int o0   = blockIdx.x * OPB;     // 16 o-groups
    const int tile = blockIdx.y;           // 256 tiles of 32x32
    const int h0   = (tile & 15) << 5;
    const int w0   = (tile >> 4) << 5;
    const int t    = threadIdx.x;
    const int ww4  = t & 7;                // float4 column within tile
    const int hh   = t >> 3;               // row 0..31

    __shared__ float Lhs[OPB * CIN * 32 * RANKS];   // 8 KB
    __shared__ float Lws[OPB * CIN * 32 * RANKS];   // 8 KB

    {
        const float4* __restrict__ L4 = (const float4*)L;
        float4* __restrict__ LhsV = (float4*)Lhs;
        float4* __restrict__ LwsV = (float4*)Lws;
#pragma unroll
        for (int j = 0; j < 4; ++j) {                   // 1024 float4 total
            int idx  = t + 256 * j;
            int side = idx >> 9;           // 0: h-side, 1: w-side
            int rem  = idx & 511;          // o2*128 + c*32 + d
            int o2   = rem >> 7;
            int c    = (rem >> 5) & 3;
            int d    = rem & 31;
            int base = side ? w0 : h0;
            float4 v = L4[((o0 + o2) * CIN + c) * DIMS + base + d];
            (side ? LwsV : LhsV)[rem] = v;
        }
    }
    __syncthreads();

    // Per-thread T registers: Tr[o2][c] = T[o0+o2, c, h0+hh, w0+4*ww4 .. +3]
    float4 Tr[OPB][CIN];
    {
        const float4* __restrict__ Lh4 = (const float4*)Lhs;
        const float4* __restrict__ Lw4 = (const float4*)Lws;
#pragma unroll
        for (int o2 = 0; o2 < OPB; ++o2)
#pragma unroll
            for (int c = 0; c < CIN; ++c) {
                float4 lh  = Lh4[(o2 * CIN + c) * 32 + hh];
                float4 wv0 = Lw4[(o2 * CIN + c) * 32 + 4 * ww4 + 0];
                float4 wv1 = Lw4[(o2 * CIN + c) * 32 + 4 * ww4 + 1];
                float4 wv2 = Lw4[(o2 * CIN + c) * 32 + 4 * ww4 + 2];
                float4 wv3 = Lw4[(o2 * CIN + c) * 32 + 4 * ww4 + 3];
                Tr[o2][c].x = lh.x * wv0.x + lh.y * wv0.y + lh.z * wv0.z + lh.w * wv0.w;
                Tr[o2][c].y = lh.x * wv1.x + lh.y * wv1.y + lh.z * wv1.z + lh.w * wv1.w;
                Tr[o2][c].z = lh.x * wv2.x + lh.y * wv2.y + lh.z * wv2.z + lh.w * wv2.w;
                Tr[o2][c].w = lh.x * wv3.x + lh.y * wv3.y + lh.z * wv3.z + lh.w * wv3.w;
            }
    }

    const float4* __restrict__ X4 = (const float4*)X;
    f32x4* __restrict__ out4      = (f32x4*)out;
    const float* __restrict__ rs  = sums;
    const float* __restrict__ cs  = sums + SUMS_ELEMS;

    float bv[OPB];
#pragma unroll
    for (int o2 = 0; o2 < OPB; ++o2) bv[o2] = bias[o0 + o2];

    const int hg  = h0 + hh;
    const int wgb = w0 + 4 * ww4;
    // diagonal masks (independent of n, o)
    const bool z0 = (hg == wgb), z1 = (hg == wgb + 1), z2 = (hg == wgb + 2), z3 = (hg == wgb + 3);
    const size_t xoff = (size_t)hg * (DIMS / 4) + (w0 >> 2) + ww4;  // float4 units

    for (int n = 0; n < NB; ++n) {
        float4 p[OPB];
#pragma unroll
        for (int o2 = 0; o2 < OPB; ++o2) p[o2] = (float4){0.f, 0.f, 0.f, 0.f};
#pragma unroll
        for (int c = 0; c < CIN; ++c) {
            float4 xv = X4[(size_t)(n * CIN + c) * (DIMS * DIMS / 4) + xoff];
#pragma unroll
            for (int o2 = 0; o2 < OPB; ++o2) {
                p[o2].x += xv.x * Tr[o2][c].x;
                p[o2].y += xv.y * Tr[o2][c].y;
                p[o2].z += xv.z * Tr[o2][c].z;
                p[o2].w += xv.w * Tr[o2][c].w;
            }
        }
#pragma unroll
        for (int o2 = 0; o2 < OPB; ++o2) {
            int oo = o0 + o2;
            float  rv = rs[(n * COUT + oo) * DIMS + hg] + bv[o2];
            float4 cv = *(const float4*)&cs[(n * COUT + oo) * DIMS + wgb];
            f32x4 ov;
            ov.x = z0 ? 0.f : (rv + cv.x - p[o2].x);
            ov.y = z1 ? 0.f : (rv + cv.y - p[o2].y);
            ov.z = z2 ? 0.f : (rv + cv.z - p[o2].z);
            ov.w = z3 ? 0.f : (rv + cv.w - p[o2].w);
            __builtin_nontemporal_store(ov,
                &out4[((size_t)(n * COUT + oo) * DIMS + hg) * (DIMS / 4) + (w0 >> 2) + ww4]);
        }
    }
}

// ---------------------------------------------------------------------------
extern "C" void kernel_launch(void* const* d_in, const int* in_sizes, int n_in,
                              void* d_out, int out_size, void* d_ws, size_t ws_size,
                              hipStream_t stream) {
    (void)in_sizes; (void)n_in; (void)out_size; (void)ws_size;
    const float* X    = (const float*)d_in[0];
    const float* L    = (const float*)d_in[1];
    const float* bias = (const float*)d_in[2];
    float* out = (float*)d_out;
    float* ws  = (float*)d_ws;

    float* Lpk  = ws;                 // 524288 floats
    float* sums = ws + LPK_ELEMS;     // 2 * 262144 floats

    pack_L<<<LPK_ELEMS / 256, 256, 0, stream>>>(L, Lpk);
    sums_kernel<<<dim3(256, 2), 256, 0, stream>>>(X, Lpk, sums);
    final_kernel<<<dim3(COUT / OPB, 256), 256, 0, stream>>>(X, L, bias, sums, out);
}